// Round 7
// baseline (109.195 us; speedup 1.0000x reference)
//
#include <hip/hip_runtime.h>

#define N 4096
#define TSTEPS 3
#define FEAT 36
#define NVIS 6
#define HID 256
#define DIN 18   // TSTEPS*NVIS
#define XP 20    // padded x row pitch (80 B -> 16B-aligned float4 loads)
#define DOUT 2

typedef __attribute__((ext_vector_type(8))) short bf16x8;   // 8 bf16 = 4 VGPR
typedef __attribute__((ext_vector_type(4))) float f32x4;

__device__ __forceinline__ short f2bf(float f) {
    unsigned u = __builtin_bit_cast(unsigned, f);
    unsigned r = (u + 0x7FFFu + ((u >> 16) & 1u)) >> 16;   // RNE
    return (short)r;
}

// ---------------- Prep (fused): vis->xall(padded)  +  W1,W2 -> bf16 frags ---
__global__ void k_prep(const float* __restrict__ vis, const float* __restrict__ Wv,
                       const float* __restrict__ bv, float* __restrict__ xall,
                       const float* __restrict__ W1, const float* __restrict__ W2,
                       short* __restrict__ Wp) {
    if (blockIdx.x < 288) {
        int o = blockIdx.x * 256 + threadIdx.x;
        if (o >= N * DIN) return;
        int j  = o / DIN;
        int ct = o - j * DIN;
        int t  = ct / NVIS;
        int c  = ct - t * NVIS;
        const float* vrow = vis + (size_t)j * (TSTEPS * FEAT) + t * FEAT;
        float acc = bv[c];
#pragma unroll
        for (int f = 0; f < FEAT; ++f) acc += vrow[f] * Wv[f * NVIS + c];
        xall[(size_t)j * XP + ct] = acc;
    } else {
        int t = (blockIdx.x - 288) * 256 + threadIdx.x;   // 0..131071
        int L  = t >> 16;
        int e  = t & 65535;
        int jj = e & 7;
        int l  = (e >> 3) & 63;
        int j  = (e >> 9) & 15;
        int s  = e >> 13;
        int k  = s * 32 + ((l >> 4) << 3) + jj;
        int n  = (j << 4) + (l & 15);
        const float* W = L ? W2 : W1;
        Wp[t] = f2bf(W[k * HID + n]);
    }
}

// One chunk of a-data: 2 rows x 12 consecutive floats (4 j's) per lane.
struct AChunk { float4 u0, u1, u2, v0, v1, v2; };

__device__ __forceinline__ AChunk aload(const float* __restrict__ a0,
                                        const float* __restrict__ a1,
                                        int lane, int ch) {
    AChunk d;
    const size_t jb = (size_t)(ch * 256 + lane * 4) * 3;
    const float4* p0 = (const float4*)(a0 + jb);
    const float4* p1 = (const float4*)(a1 + jb);
    d.u0 = p0[0]; d.u1 = p0[1]; d.u2 = p0[2];
    d.v0 = p1[0]; d.v1 = p1[1]; d.v2 = p1[2];
    return d;
}

__device__ __forceinline__ void compute(const AChunk& d, const float* __restrict__ xall,
                                        int lane, int ch,
                                        float acc[2][3][6], float s[2][2]) {
    const float av0[4][3] = {{d.u0.x,d.u0.y,d.u0.z},{d.u0.w,d.u1.x,d.u1.y},
                             {d.u1.z,d.u1.w,d.u2.x},{d.u2.y,d.u2.z,d.u2.w}};
    const float av1[4][3] = {{d.v0.x,d.v0.y,d.v0.z},{d.v0.w,d.v1.x,d.v1.y},
                             {d.v1.z,d.v1.w,d.v2.x},{d.v2.y,d.v2.z,d.v2.w}};
#pragma unroll
    for (int q = 0; q < 4; ++q) {
        const float* xr = xall + (size_t)(ch * 256 + lane * 4 + q) * XP;
        float4 x0 = *(const float4*)(xr);
        float4 x1 = *(const float4*)(xr + 4);
        float4 x2 = *(const float4*)(xr + 8);
        float4 x3 = *(const float4*)(xr + 12);
        float2 x4 = *(const float2*)(xr + 16);
        const float xv[18] = {x0.x,x0.y,x0.z,x0.w, x1.x,x1.y,x1.z,x1.w,
                              x2.x,x2.y,x2.z,x2.w, x3.x,x3.y,x3.z,x3.w,
                              x4.x,x4.y};
#pragma unroll
        for (int t = 0; t < 3; ++t)
#pragma unroll
            for (int c = 0; c < 6; ++c) {
                acc[0][t][c] += av0[q][t] * xv[t*6+c];
                acc[1][t][c] += av1[q][t] * xv[t*6+c];
            }
        s[0][0] += av0[q][1]; s[0][1] += av0[q][2];
        s[1][0] += av1[q][1]; s[1][1] += av1[q][2];
    }
}

// ---------------- Fused: barrier-free message stream + per-row MLP tail -----
// 512 blocks x 256 thr (2 blocks/CU). Each wave owns 2 rows; 16 chunks of 256 j,
// x read directly from L2-resident padded xall. No __syncthreads in the stream.
template<int FUSE>
__global__ void k_msg_mlp(const float* __restrict__ a, const float* __restrict__ xall,
                          float* __restrict__ xagg,
                          const short* __restrict__ Wp,
                          const float* __restrict__ W0, const float* __restrict__ b0,
                          const float* __restrict__ b1, const float* __restrict__ b2,
                          const float* __restrict__ Wpf, const float* __restrict__ bp,
                          float* __restrict__ u_out) {
    __shared__ struct {
        float xa[8][DIN];                     // block's 8 xagg rows
        short hA[16 * 256];                   // bf16 h, XOR-swizzled rows
        short hB[16 * 256];
        float h3[16 * 257];
    } sm;                                     // 33408 B
    const int tid  = threadIdx.x;
    const int lane = tid & 63;
    const int wave = tid >> 6;
    const int row0 = blockIdx.x * 8;
    const int row_base = row0 + wave * 2;

    const float* a0 = a + (size_t)row_base       * (N * 3);
    const float* a1 = a + (size_t)(row_base + 1) * (N * 3);

    float acc[2][3][6];
    float s[2][2];
#pragma unroll
    for (int r = 0; r < 2; ++r) {
#pragma unroll
        for (int t = 0; t < 3; ++t)
#pragma unroll
            for (int c = 0; c < 6; ++c) acc[r][t][c] = 0.f;
        s[r][0] = 0.f; s[r][1] = 0.f;
    }

    // software-pipelined stream: prefetch next chunk while computing current
    {
        AChunk A = aload(a0, a1, lane, 0);
#pragma unroll
        for (int ch = 0; ch < 16; ch += 2) {
            AChunk B = aload(a0, a1, lane, ch + 1);
            compute(A, xall, lane, ch, acc, s);
            if (ch + 2 < 16) A = aload(a0, a1, lane, ch + 2);
            compute(B, xall, lane, ch + 1, acc, s);
        }
    }

    // butterfly reduce (registers only)
#pragma unroll
    for (int m = 1; m < 64; m <<= 1) {
#pragma unroll
        for (int r = 0; r < 2; ++r) {
#pragma unroll
            for (int t = 0; t < 3; ++t)
#pragma unroll
                for (int c = 0; c < 6; ++c)
                    acc[r][t][c] += __shfl_xor(acc[r][t][c], m, 64);
            s[r][0] += __shfl_xor(s[r][0], m, 64);
            s[r][1] += __shfl_xor(s[r][1], m, 64);
        }
    }

    if (lane == 0) {
#pragma unroll
        for (int r = 0; r < 2; ++r) {
            const float s1 = s[r][0], s2 = s[r][1];
            float* xrow = sm.xa[wave * 2 + r];
#pragma unroll
            for (int c = 0; c < 6; ++c) {
                xrow[c]      = acc[r][2][c];
                xrow[6 + c]  = acc[r][1][c] * s2;
                xrow[12 + c] = acc[r][0][c] * s1 * s2;
            }
        }
    }
    __syncthreads();

    // coalesced xagg write (8 rows = 144 consecutive floats)
    for (int idx = tid; idx < 8 * DIN; idx += 256) {
        int r = idx / DIN, e = idx - r * DIN;
        xagg[(size_t)(row0 + r) * DIN + e] = sm.xa[r][e];
    }

    if (!FUSE) return;

    { // ---- layer 0 (K=18, f32 VALU): thread -> 1 row x 8 neurons ----
        const int row = tid >> 5;            // 0..7
        const int n0  = (tid & 31) * 8;
        float accv[8];
#pragma unroll
        for (int jn = 0; jn < 8; ++jn) accv[jn] = b0[n0 + jn];
        for (int k = 0; k < DIN; ++k) {
            float4 wa = *(const float4*)&W0[k * HID + n0];
            float4 wb = *(const float4*)&W0[k * HID + n0 + 4];
            const float w[8] = {wa.x,wa.y,wa.z,wa.w, wb.x,wb.y,wb.z,wb.w};
            float xr = sm.xa[row][k];
#pragma unroll
            for (int jn = 0; jn < 8; ++jn) accv[jn] += xr * w[jn];
        }
        bf16x8 v;
#pragma unroll
        for (int jn = 0; jn < 8; ++jn) v[jn] = f2bf(fmaxf(accv[jn], 0.f));
        *(bf16x8*)&sm.hA[(row * 256 + n0) ^ ((row & 7) << 3)] = v;
    }
    __syncthreads();

    // ---- layers 1 & 2: MFMA 16x16x32 bf16 (rows 8-15 garbage, confined) ----
    const int arow = lane & 15;
    const int kgrp = (lane >> 4) << 3;
    const int wv   = wave;
#pragma unroll 1
    for (int L = 0; L < 2; ++L) {
        const short* hsrc = L ? sm.hB : sm.hA;
        const float* bias = L ? b2 : b1;
        const short* WpL  = Wp + L * 65536;

        bf16x8 Af[8];
#pragma unroll
        for (int ks = 0; ks < 8; ++ks)
            Af[ks] = *(const bf16x8*)&hsrc[(arow * 256 + ks * 32 + kgrp) ^ ((arow & 7) << 3)];

        f32x4 c4[4];
#pragma unroll
        for (int jt = 0; jt < 4; ++jt) {
            float b = bias[wv * 64 + jt * 16 + (lane & 15)];
            c4[jt] = (f32x4){b, b, b, b};
        }
#pragma unroll
        for (int ks = 0; ks < 8; ++ks) {
#pragma unroll
            for (int jt = 0; jt < 4; ++jt) {
                int j = wv * 4 + jt;
                bf16x8 Bf = *(const bf16x8*)&WpL[(((ks * 16 + j) * 64) + lane) * 8];
                c4[jt] = __builtin_amdgcn_mfma_f32_16x16x32_bf16(Af[ks], Bf, c4[jt], 0, 0, 0);
            }
        }
#pragma unroll
        for (int jt = 0; jt < 4; ++jt) {
            int n = wv * 64 + jt * 16 + (lane & 15);
#pragma unroll
            for (int q = 0; q < 4; ++q) {
                int row = ((lane >> 4) << 2) + q;
                float v = fmaxf(c4[jt][q], 0.f);
                if (L == 0) sm.hB[(row * 256 + n) ^ ((row & 7) << 3)] = f2bf(v);
                else        sm.h3[row * 257 + n] = v;
            }
        }
        __syncthreads();
    }

    // ---- final layer 256 -> 2 for 8 rows: tid = r*16 + d*8 + ks ----
    if (tid < 128) {
        const int r  = tid >> 4;        // 0..7
        const int d  = (tid >> 3) & 1;
        const int ks = tid & 7;
        float accf = 0.f;
        const float* hr = &sm.h3[r * 257 + ks * 32];
#pragma unroll
        for (int i = 0; i < 32; ++i) accf += hr[i] * Wpf[(ks * 32 + i) * DOUT + d];
        accf += __shfl_xor(accf, 1, 64);
        accf += __shfl_xor(accf, 2, 64);
        accf += __shfl_xor(accf, 4, 64);
        if (ks == 0) u_out[(size_t)(row0 + r) * DOUT + d] = accf + bp[d];
    }
}

// ---------------- Fallback VALU MLP (only if workspace too small) -----------
#define HPITCH 20
__global__ __launch_bounds__(512, 2) void k_mlp(const float* __restrict__ xagg,
                      const float* __restrict__ W0, const float* __restrict__ b0,
                      const float* __restrict__ W1, const float* __restrict__ b1,
                      const float* __restrict__ W2, const float* __restrict__ b2,
                      const float* __restrict__ Wpf, const float* __restrict__ bp,
                      float* __restrict__ u_out) {
    __shared__ float xa[16][DIN];
    __shared__ float hb[2][HID][HPITCH];
    const int tid   = threadIdx.x;
    const int n     = tid & 255;
    const int rbase = (tid >> 8) * 8;
    const int base  = blockIdx.x * 16;

    for (int idx = tid; idx < 16 * DIN; idx += 512) {
        int r = idx / DIN, e = idx - r * DIN;
        xa[r][e] = xagg[(size_t)(base + r) * DIN + e];
    }
    __syncthreads();
    {
        float accv[8];
#pragma unroll
        for (int r = 0; r < 8; ++r) accv[r] = b0[n];
        for (int k = 0; k < DIN; ++k) {
            float w = W0[k * HID + n];
#pragma unroll
            for (int r = 0; r < 8; ++r) accv[r] += xa[rbase + r][k] * w;
        }
#pragma unroll
        for (int r = 0; r < 8; ++r) hb[0][n][rbase + r] = fmaxf(accv[r], 0.f);
    }
    __syncthreads();
    {
        float accv[8];
#pragma unroll
        for (int r = 0; r < 8; ++r) accv[r] = b1[n];
        for (int k = 0; k < HID; ++k) {
            float w = W1[k * HID + n];
            const float4* hp = (const float4*)&hb[0][k][rbase];
            float4 h0 = hp[0], h1 = hp[1];
            const float hv[8] = {h0.x,h0.y,h0.z,h0.w, h1.x,h1.y,h1.z,h1.w};
#pragma unroll
            for (int r = 0; r < 8; ++r) accv[r] += hv[r] * w;
        }
#pragma unroll
        for (int r = 0; r < 8; ++r) hb[1][n][rbase + r] = fmaxf(accv[r], 0.f);
    }
    __syncthreads();
    {
        float accv[8];
#pragma unroll
        for (int r = 0; r < 8; ++r) accv[r] = b2[n];
        for (int k = 0; k < HID; ++k) {
            float w = W2[k * HID + n];
            const float4* hp = (const float4*)&hb[1][k][rbase];
            float4 h0 = hp[0], h1 = hp[1];
            const float hv[8] = {h0.x,h0.y,h0.z,h0.w, h1.x,h1.y,h1.z,h1.w};
#pragma unroll
            for (int r = 0; r < 8; ++r) accv[r] += hv[r] * w;
        }
#pragma unroll
        for (int r = 0; r < 8; ++r) hb[0][n][rbase + r] = fmaxf(accv[r], 0.f);
    }
    __syncthreads();
    if (tid < 32) {
        int r = tid >> 1, d = tid & 1;
        float acc = bp[d];
        for (int k = 0; k < HID; ++k) acc += hb[0][k][r] * Wpf[k * DOUT + d];
        u_out[(size_t)(base + r) * DOUT + d] = acc;
    }
}

extern "C" void kernel_launch(void* const* d_in, const int* in_sizes, int n_in,
                              void* d_out, int out_size, void* d_ws, size_t ws_size,
                              hipStream_t stream) {
    const float* vis  = (const float*)d_in[0];
    const float* anet = (const float*)d_in[1];
    const float* Wv   = (const float*)d_in[2];
    const float* bv   = (const float*)d_in[3];
    const float* W0   = (const float*)d_in[4];
    const float* b0   = (const float*)d_in[5];
    const float* W1   = (const float*)d_in[6];
    const float* b1   = (const float*)d_in[7];
    const float* W2   = (const float*)d_in[8];
    const float* b2   = (const float*)d_in[9];
    const float* Wpf  = (const float*)d_in[10];
    const float* bp   = (const float*)d_in[11];

    float* xagg  = (float*)d_out;                  // 4096*18
    float* u_out = (float*)d_out + (size_t)N*DIN;  // 4096*2
    float* xall  = (float*)d_ws;                   // 4096*20 padded (327 KB)
    short* Wpk   = (short*)((char*)d_ws + (512 << 10));  // 256 KB bf16 frags

    const bool fuse = ws_size >= (512 << 10) + 131072 * sizeof(short);

    if (fuse) {
        k_prep<<<800, 256, 0, stream>>>(vis, Wv, bv, xall, W1, W2, Wpk);
        k_msg_mlp<1><<<N / 8, 256, 0, stream>>>(anet, xall, xagg, Wpk,
                                                W0, b0, b1, b2, Wpf, bp, u_out);
    } else {
        k_prep<<<288, 256, 0, stream>>>(vis, Wv, bv, xall, W1, W2, Wpk);
        k_msg_mlp<0><<<N / 8, 256, 0, stream>>>(anet, xall, xagg, Wpk,
                                                W0, b0, b1, b2, Wpf, bp, u_out);
        k_mlp<<<N / 16, 512, 0, stream>>>(xagg, W0, b0, W1, b1, W2, b2, Wpf, bp, u_out);
    }
}

// Round 8
// 104.147 us; speedup vs baseline: 1.0485x; 1.0485x over previous
//
#include <hip/hip_runtime.h>

#define N 4096
#define TSTEPS 3
#define FEAT 36
#define NVIS 6
#define HID 256
#define DIN 18   // TSTEPS*NVIS
#define XP 20    // padded x row pitch (80 B -> 16B-aligned float4 loads)
#define DOUT 2

typedef __attribute__((ext_vector_type(8))) short bf16x8;   // 8 bf16 = 4 VGPR
typedef __attribute__((ext_vector_type(4))) float f32x4;

__device__ __forceinline__ short f2bf(float f) {
    unsigned u = __builtin_bit_cast(unsigned, f);
    unsigned r = (u + 0x7FFFu + ((u >> 16) & 1u)) >> 16;   // RNE
    return (short)r;
}

// ---------------- Prep (fused): vis->xall(padded)  +  W1,W2 -> bf16 frags ---
__global__ void k_prep(const float* __restrict__ vis, const float* __restrict__ Wv,
                       const float* __restrict__ bv, float* __restrict__ xall,
                       const float* __restrict__ W1, const float* __restrict__ W2,
                       short* __restrict__ Wp) {
    if (blockIdx.x < 288) {
        int o = blockIdx.x * 256 + threadIdx.x;
        if (o >= N * DIN) return;
        int j  = o / DIN;
        int ct = o - j * DIN;
        int t  = ct / NVIS;
        int c  = ct - t * NVIS;
        const float* vrow = vis + (size_t)j * (TSTEPS * FEAT) + t * FEAT;
        float acc = bv[c];
#pragma unroll
        for (int f = 0; f < FEAT; ++f) acc += vrow[f] * Wv[f * NVIS + c];
        xall[(size_t)j * XP + ct] = acc;
    } else {
        int t = (blockIdx.x - 288) * 256 + threadIdx.x;   // 0..131071
        int L  = t >> 16;
        int e  = t & 65535;
        int jj = e & 7;
        int l  = (e >> 3) & 63;
        int j  = (e >> 9) & 15;
        int s  = e >> 13;
        int k  = s * 32 + ((l >> 4) << 3) + jj;
        int n  = (j << 4) + (l & 15);
        const float* W = L ? W2 : W1;
        Wp[t] = f2bf(W[k * HID + n]);
    }
}

// One chunk of a-data: 2 rows x 12 consecutive floats (4 j's) per lane.
struct AChunk { float4 u0, u1, u2, v0, v1, v2; };
// One chunk of x-data: 4 j-rows x 18 floats per lane.
struct XC { float4 v[4][4]; float2 w[4]; };

__device__ __forceinline__ AChunk aload(const float* __restrict__ a0,
                                        const float* __restrict__ a1,
                                        int lane, int ch) {
    AChunk d;
    const size_t jb = (size_t)(ch * 256 + lane * 4) * 3;
    const float4* p0 = (const float4*)(a0 + jb);
    const float4* p1 = (const float4*)(a1 + jb);
    d.u0 = p0[0]; d.u1 = p0[1]; d.u2 = p0[2];
    d.v0 = p1[0]; d.v1 = p1[1]; d.v2 = p1[2];
    return d;
}

__device__ __forceinline__ XC xload(const float* __restrict__ xall, int lane, int ch) {
    XC r;
#pragma unroll
    for (int q = 0; q < 4; ++q) {
        const float* xr = xall + (size_t)(ch * 256 + lane * 4 + q) * XP;
        r.v[q][0] = *(const float4*)(xr);
        r.v[q][1] = *(const float4*)(xr + 4);
        r.v[q][2] = *(const float4*)(xr + 8);
        r.v[q][3] = *(const float4*)(xr + 12);
        r.w[q]    = *(const float2*)(xr + 16);
    }
    return r;
}

__device__ __forceinline__ void compute(const AChunk& d, const XC& X,
                                        float acc[2][3][6], float s[2][2]) {
    const float av0[4][3] = {{d.u0.x,d.u0.y,d.u0.z},{d.u0.w,d.u1.x,d.u1.y},
                             {d.u1.z,d.u1.w,d.u2.x},{d.u2.y,d.u2.z,d.u2.w}};
    const float av1[4][3] = {{d.v0.x,d.v0.y,d.v0.z},{d.v0.w,d.v1.x,d.v1.y},
                             {d.v1.z,d.v1.w,d.v2.x},{d.v2.y,d.v2.z,d.v2.w}};
#pragma unroll
    for (int q = 0; q < 4; ++q) {
        const float xv[18] = {X.v[q][0].x, X.v[q][0].y, X.v[q][0].z, X.v[q][0].w,
                              X.v[q][1].x, X.v[q][1].y, X.v[q][1].z, X.v[q][1].w,
                              X.v[q][2].x, X.v[q][2].y, X.v[q][2].z, X.v[q][2].w,
                              X.v[q][3].x, X.v[q][3].y, X.v[q][3].z, X.v[q][3].w,
                              X.w[q].x,    X.w[q].y};
#pragma unroll
        for (int t = 0; t < 3; ++t)
#pragma unroll
            for (int c = 0; c < 6; ++c) {
                acc[0][t][c] += av0[q][t] * xv[t*6+c];
                acc[1][t][c] += av1[q][t] * xv[t*6+c];
            }
        s[0][0] += av0[q][1]; s[0][1] += av0[q][2];
        s[1][0] += av1[q][1]; s[1][1] += av1[q][2];
    }
}

// ---------------- Fused: barrier-free message stream + per-row MLP tail -----
// 512 blocks x 256 thr (2 blocks/CU). Each wave owns 2 rows; 16 chunks of 256 j.
// launch_bounds(256,2): VGPR cap 256 so the a+x register pipeline fits
// (R7 failure: default alloc = 64 VGPR -> load dribble -> 751 GB/s).
template<int FUSE>
__global__ __launch_bounds__(256, 2)
void k_msg_mlp(const float* __restrict__ a, const float* __restrict__ xall,
               float* __restrict__ xagg,
               const short* __restrict__ Wp,
               const float* __restrict__ W0, const float* __restrict__ b0,
               const float* __restrict__ b1, const float* __restrict__ b2,
               const float* __restrict__ Wpf, const float* __restrict__ bp,
               float* __restrict__ u_out) {
    __shared__ struct {
        float xa[8][DIN];                     // block's 8 xagg rows
        short hA[16 * 256];                   // bf16 h, XOR-swizzled rows
        short hB[16 * 256];
        float h3[16 * 257];
    } sm;                                     // 33408 B
    const int tid  = threadIdx.x;
    const int lane = tid & 63;
    const int wave = tid >> 6;
    const int row0 = blockIdx.x * 8;
    const int row_base = row0 + wave * 2;

    const float* a0 = a + (size_t)row_base       * (N * 3);
    const float* a1 = a + (size_t)(row_base + 1) * (N * 3);

    float acc[2][3][6];
    float s[2][2];
#pragma unroll
    for (int r = 0; r < 2; ++r) {
#pragma unroll
        for (int t = 0; t < 3; ++t)
#pragma unroll
            for (int c = 0; c < 6; ++c) acc[r][t][c] = 0.f;
        s[r][0] = 0.f; s[r][1] = 0.f;
    }

    // barrier-free stream, explicit 1-chunk-ahead register pipeline of a AND x
    {
        AChunk ac = aload(a0, a1, lane, 0);
        XC     xc = xload(xall, lane, 0);
#pragma unroll
        for (int ch = 0; ch < 16; ++ch) {
            AChunk an; XC xn;
            if (ch + 1 < 16) {
                an = aload(a0, a1, lane, ch + 1);
                xn = xload(xall, lane, ch + 1);
            }
            compute(ac, xc, acc, s);
            ac = an; xc = xn;
        }
    }

    // butterfly reduce (registers only)
#pragma unroll
    for (int m = 1; m < 64; m <<= 1) {
#pragma unroll
        for (int r = 0; r < 2; ++r) {
#pragma unroll
            for (int t = 0; t < 3; ++t)
#pragma unroll
                for (int c = 0; c < 6; ++c)
                    acc[r][t][c] += __shfl_xor(acc[r][t][c], m, 64);
            s[r][0] += __shfl_xor(s[r][0], m, 64);
            s[r][1] += __shfl_xor(s[r][1], m, 64);
        }
    }

    if (lane == 0) {
#pragma unroll
        for (int r = 0; r < 2; ++r) {
            const float s1 = s[r][0], s2 = s[r][1];
            float* xrow = sm.xa[wave * 2 + r];
#pragma unroll
            for (int c = 0; c < 6; ++c) {
                xrow[c]      = acc[r][2][c];
                xrow[6 + c]  = acc[r][1][c] * s2;
                xrow[12 + c] = acc[r][0][c] * s1 * s2;
            }
        }
    }
    __syncthreads();

    // coalesced xagg write (8 rows = 144 consecutive floats)
    for (int idx = tid; idx < 8 * DIN; idx += 256) {
        int r = idx / DIN, e = idx - r * DIN;
        xagg[(size_t)(row0 + r) * DIN + e] = sm.xa[r][e];
    }

    if (!FUSE) return;

    { // ---- layer 0 (K=18, f32 VALU): thread -> 1 row x 8 neurons ----
        const int row = tid >> 5;            // 0..7
        const int n0  = (tid & 31) * 8;
        float accv[8];
#pragma unroll
        for (int jn = 0; jn < 8; ++jn) accv[jn] = b0[n0 + jn];
        for (int k = 0; k < DIN; ++k) {
            float4 wa = *(const float4*)&W0[k * HID + n0];
            float4 wb = *(const float4*)&W0[k * HID + n0 + 4];
            const float w[8] = {wa.x,wa.y,wa.z,wa.w, wb.x,wb.y,wb.z,wb.w};
            float xr = sm.xa[row][k];
#pragma unroll
            for (int jn = 0; jn < 8; ++jn) accv[jn] += xr * w[jn];
        }
        bf16x8 v;
#pragma unroll
        for (int jn = 0; jn < 8; ++jn) v[jn] = f2bf(fmaxf(accv[jn], 0.f));
        *(bf16x8*)&sm.hA[(row * 256 + n0) ^ ((row & 7) << 3)] = v;
    }
    __syncthreads();

    // ---- layers 1 & 2: MFMA 16x16x32 bf16 (rows 8-15 garbage, confined) ----
    const int arow = lane & 15;
    const int kgrp = (lane >> 4) << 3;
    const int wv   = wave;
#pragma unroll 1
    for (int L = 0; L < 2; ++L) {
        const short* hsrc = L ? sm.hB : sm.hA;
        const float* bias = L ? b2 : b1;
        const short* WpL  = Wp + L * 65536;

        bf16x8 Af[8];
#pragma unroll
        for (int ks = 0; ks < 8; ++ks)
            Af[ks] = *(const bf16x8*)&hsrc[(arow * 256 + ks * 32 + kgrp) ^ ((arow & 7) << 3)];

        f32x4 c4[4];
#pragma unroll
        for (int jt = 0; jt < 4; ++jt) {
            float b = bias[wv * 64 + jt * 16 + (lane & 15)];
            c4[jt] = (f32x4){b, b, b, b};
        }
#pragma unroll
        for (int ks = 0; ks < 8; ++ks) {
#pragma unroll
            for (int jt = 0; jt < 4; ++jt) {
                int j = wv * 4 + jt;
                bf16x8 Bf = *(const bf16x8*)&WpL[(((ks * 16 + j) * 64) + lane) * 8];
                c4[jt] = __builtin_amdgcn_mfma_f32_16x16x32_bf16(Af[ks], Bf, c4[jt], 0, 0, 0);
            }
        }
#pragma unroll
        for (int jt = 0; jt < 4; ++jt) {
            int n = wv * 64 + jt * 16 + (lane & 15);
#pragma unroll
            for (int q = 0; q < 4; ++q) {
                int row = ((lane >> 4) << 2) + q;
                float v = fmaxf(c4[jt][q], 0.f);
                if (L == 0) sm.hB[(row * 256 + n) ^ ((row & 7) << 3)] = f2bf(v);
                else        sm.h3[row * 257 + n] = v;
            }
        }
        __syncthreads();
    }

    // ---- final layer 256 -> 2 for 8 rows: tid = r*16 + d*8 + ks ----
    if (tid < 128) {
        const int r  = tid >> 4;        // 0..7
        const int d  = (tid >> 3) & 1;
        const int ks = tid & 7;
        float accf = 0.f;
        const float* hr = &sm.h3[r * 257 + ks * 32];
#pragma unroll
        for (int i = 0; i < 32; ++i) accf += hr[i] * Wpf[(ks * 32 + i) * DOUT + d];
        accf += __shfl_xor(accf, 1, 64);
        accf += __shfl_xor(accf, 2, 64);
        accf += __shfl_xor(accf, 4, 64);
        if (ks == 0) u_out[(size_t)(row0 + r) * DOUT + d] = accf + bp[d];
    }
}

// ---------------- Fallback VALU MLP (only if workspace too small) -----------
#define HPITCH 20
__global__ __launch_bounds__(512, 2) void k_mlp(const float* __restrict__ xagg,
                      const float* __restrict__ W0, const float* __restrict__ b0,
                      const float* __restrict__ W1, const float* __restrict__ b1,
                      const float* __restrict__ W2, const float* __restrict__ b2,
                      const float* __restrict__ Wpf, const float* __restrict__ bp,
                      float* __restrict__ u_out) {
    __shared__ float xa[16][DIN];
    __shared__ float hb[2][HID][HPITCH];
    const int tid   = threadIdx.x;
    const int n     = tid & 255;
    const int rbase = (tid >> 8) * 8;
    const int base  = blockIdx.x * 16;

    for (int idx = tid; idx < 16 * DIN; idx += 512) {
        int r = idx / DIN, e = idx - r * DIN;
        xa[r][e] = xagg[(size_t)(base + r) * DIN + e];
    }
    __syncthreads();
    {
        float accv[8];
#pragma unroll
        for (int r = 0; r < 8; ++r) accv[r] = b0[n];
        for (int k = 0; k < DIN; ++k) {
            float w = W0[k * HID + n];
#pragma unroll
            for (int r = 0; r < 8; ++r) accv[r] += xa[rbase + r][k] * w;
        }
#pragma unroll
        for (int r = 0; r < 8; ++r) hb[0][n][rbase + r] = fmaxf(accv[r], 0.f);
    }
    __syncthreads();
    {
        float accv[8];
#pragma unroll
        for (int r = 0; r < 8; ++r) accv[r] = b1[n];
        for (int k = 0; k < HID; ++k) {
            float w = W1[k * HID + n];
            const float4* hp = (const float4*)&hb[0][k][rbase];
            float4 h0 = hp[0], h1 = hp[1];
            const float hv[8] = {h0.x,h0.y,h0.z,h0.w, h1.x,h1.y,h1.z,h1.w};
#pragma unroll
            for (int r = 0; r < 8; ++r) accv[r] += hv[r] * w;
        }
#pragma unroll
        for (int r = 0; r < 8; ++r) hb[1][n][rbase + r] = fmaxf(accv[r], 0.f);
    }
    __syncthreads();
    {
        float accv[8];
#pragma unroll
        for (int r = 0; r < 8; ++r) accv[r] = b2[n];
        for (int k = 0; k < HID; ++k) {
            float w = W2[k * HID + n];
            const float4* hp = (const float4*)&hb[1][k][rbase];
            float4 h0 = hp[0], h1 = hp[1];
            const float hv[8] = {h0.x,h0.y,h0.z,h0.w, h1.x,h1.y,h1.z,h1.w};
#pragma unroll
            for (int r = 0; r < 8; ++r) accv[r] += hv[r] * w;
        }
#pragma unroll
        for (int r = 0; r < 8; ++r) hb[0][n][rbase + r] = fmaxf(accv[r], 0.f);
    }
    __syncthreads();
    if (tid < 32) {
        int r = tid >> 1, d = tid & 1;
        float acc = bp[d];
        for (int k = 0; k < HID; ++k) acc += hb[0][k][r] * Wpf[k * DOUT + d];
        u_out[(size_t)(base + r) * DOUT + d] = acc;
    }
}

extern "C" void kernel_launch(void* const* d_in, const int* in_sizes, int n_in,
                              void* d_out, int out_size, void* d_ws, size_t ws_size,
                              hipStream_t stream) {
    const float* vis  = (const float*)d_in[0];
    const float* anet = (const float*)d_in[1];
    const float* Wv   = (const float*)d_in[2];
    const float* bv   = (const float*)d_in[3];
    const float* W0   = (const float*)d_in[4];
    const float* b0   = (const float*)d_in[5];
    const float* W1   = (const float*)d_in[6];
    const float* b1   = (const float*)d_in[7];
    const float* W2   = (const float*)d_in[8];
    const float* b2   = (const float*)d_in[9];
    const float* Wpf  = (const float*)d_in[10];
    const float* bp   = (const float*)d_in[11];

    float* xagg  = (float*)d_out;                  // 4096*18
    float* u_out = (float*)d_out + (size_t)N*DIN;  // 4096*2
    float* xall  = (float*)d_ws;                   // 4096*20 padded (327 KB)
    short* Wpk   = (short*)((char*)d_ws + (512 << 10));  // 256 KB bf16 frags

    const bool fuse = ws_size >= (512 << 10) + 131072 * sizeof(short);

    if (fuse) {
        k_prep<<<800, 256, 0, stream>>>(vis, Wv, bv, xall, W1, W2, Wpk);
        k_msg_mlp<1><<<N / 8, 256, 0, stream>>>(anet, xall, xagg, Wpk,
                                                W0, b0, b1, b2, Wpf, bp, u_out);
    } else {
        k_prep<<<288, 256, 0, stream>>>(vis, Wv, bv, xall, W1, W2, Wpk);
        k_msg_mlp<0><<<N / 8, 256, 0, stream>>>(anet, xall, xagg, Wpk,
                                                W0, b0, b1, b2, Wpf, bp, u_out);
        k_mlp<<<N / 16, 512, 0, stream>>>(xagg, W0, b0, W1, b1, W2, b2, Wpf, bp, u_out);
    }
}